// Round 7
// baseline (68.375 us; speedup 1.0000x reference)
//
#include <hip/hip_runtime.h>

#define BB 32
#define CC 16
#define HH 256
#define WW 256
#define HWSZ (HH * WW)

#define TW 64                  // tile width (x)
#define TH 16                  // tile height (y)
#define NBLK (BB * (WW/TW) * (HH/TH))   // 2048 blocks
#define NXCD 8

#define SROWS 39               // staged row capacity (typ. need ~22; fallback covers tails)
#define SCOLS 101              // ODD row stride: phases {0,5,10,15} mod 32 hit all mod-4
                               // residues -> stride-4 gather lanes spread 2-way (free)
#define MAXF4 25               // staged quads occupy cols 0..99
#define KMAX 4                 // ceil(39*25/256)

typedef float f2 __attribute__((ext_vector_type(2)));
typedef float f4 __attribute__((ext_vector_type(4)));

__global__ __launch_bounds__(256) void st_lds4_kernel(
    const float* __restrict__ input,   // [B,C,H,W]
    const float* __restrict__ theta,   // [B,6]
    float* __restrict__ out)           // [B,C,H,W]
{
    __shared__ float S[2][SROWS * SCOLS];   // 31.5 KB -> 5 blocks/CU

    // Chunked XCD swizzle (2048 % 8 == 0, bijective)
    int bid = blockIdx.x;
    int wg = (bid & (NXCD - 1)) * (NBLK / NXCD) + (bid >> 3);

    int b  = wg >> 6;              // 64 tiles per image
    int r  = wg & 63;
    int yt = r >> 2;               // 16 y-tiles
    int xt = r & 3;                // 4 x-tiles

    int tid = threadIdx.x;
    int qy = tid >> 4;             // 0..15 row in tile
    int qx = tid & 15;             // 0..15 col-quad
    int oy  = yt * TH + qy;
    int oxb = xt * TW + qx * 4;    // 4 consecutive x-pixels per thread (f4 store)

    const float* th = theta + b * 6;
    float t0 = th[0], t1 = th[1], t2 = th[2];
    float t3 = th[3], t4 = th[4], t5 = th[5];

    const float step = 2.0f / 255.0f;

    // ---- staging window from tile-corner bounds (affine + monotone clip) ----
    float gxa = -1.0f + (xt * TW) * step;
    float gxb = -1.0f + (xt * TW + TW - 1) * step;
    float gya = -1.0f + (yt * TH) * step;
    float gyb = -1.0f + (yt * TH + TH - 1) * step;

    float x00 = t0 * gxa + t1 * gya + t2, x01 = t0 * gxa + t1 * gyb + t2;
    float x10 = t0 * gxb + t1 * gya + t2, x11 = t0 * gxb + t1 * gyb + t2;
    float y00 = t3 * gxa + t4 * gya + t5, y01 = t3 * gxa + t4 * gyb + t5;
    float y10 = t3 * gxb + t4 * gya + t5, y11 = t3 * gxb + t4 * gyb + t5;

    float xmn = fminf(fminf(x00, x01), fminf(x10, x11));
    float xmx = fmaxf(fmaxf(x00, x01), fmaxf(x10, x11));
    float ymn = fminf(fminf(y00, y01), fminf(y10, y11));
    float ymx = fmaxf(fmaxf(y00, y01), fmaxf(y10, y11));
    xmn = fminf(fmaxf(xmn, -1.0f), 1.0f);
    xmx = fminf(fmaxf(xmx, -1.0f), 1.0f);
    ymn = fminf(fmaxf(ymn, -1.0f), 1.0f);
    ymx = fminf(fmaxf(ymx, -1.0f), 1.0f);
    float pxmn = (xmn + 1.0f) * 127.5f, pxmx = (xmx + 1.0f) * 127.5f;
    float pymn = (ymn + 1.0f) * 127.5f, pymx = (ymx + 1.0f) * 127.5f;

    int cx0 = (int)floorf(pxmn) - 1;
    cx0 = (max(0, min(cx0, WW - 4))) & ~3;              // 16B-aligned global start
    int cxend = min((int)floorf(pxmx) + 2, WW - 1);     // inclusive
    int wf4 = (cxend - cx0 + 4) >> 2;
    wf4 = min(wf4, min(MAXF4, (WW - cx0) >> 2));
    int wcols = wf4 * 4;

    int ry0 = (int)floorf(pymn) - 1;
    ry0 = max(0, min(ry0, HH - 1));
    int ryend = min((int)floorf(pymx) + 2, HH - 1);
    int rows = min(min(ryend - ry0 + 1, SROWS), HH - ry0);
    int nf4 = rows * wf4;

    // ---- precompute stage slots ONCE (channel-invariant) ----
    int  sg[KMAX], sl[KMAX];
    bool sv[KMAX];
    #pragma unroll
    for (int k = 0; k < KMAX; ++k) {
        int idx = tid + k * 256;
        sv[k] = idx < nf4;
        int rr = idx / wf4;
        int cq = idx - rr * wf4;
        sg[k] = rr * WW + cq * 4;      // global float offset within window
        sl[k] = rr * SCOLS + cq * 4;   // LDS float offset
    }

    // ---- per-pixel offsets & weights (channel-invariant) ----
    int   off[4], goff[4];
    float w00[4], w01[4], w10[4], w11[4];
    bool  ok[4];
    float gy = -1.0f + oy * step;
    float cxp = t1 * gy + t2;
    float cyp = t4 * gy + t5;

    #pragma unroll
    for (int j = 0; j < 4; ++j) {
        float gx = -1.0f + (oxb + j) * step;
        float xs = fminf(fmaxf(t0 * gx + cxp, -1.0f), 1.0f);
        float ys = fminf(fmaxf(t3 * gx + cyp, -1.0f), 1.0f);
        float x = (xs + 1.0f) * 127.5f;
        float y = (ys + 1.0f) * 127.5f;
        // bx=min(floor(x),254), fx=x-bx in [0,1]: exact index-clamp semantics
        float bxf = fminf(floorf(x), 254.0f);
        float byf = fminf(floorf(y), 254.0f);
        float fx = x - bxf, fy = y - byf;
        int bx = (int)bxf, by = (int)byf;

        w00[j] = (1.0f - fx) * (1.0f - fy);
        w01[j] = fx * (1.0f - fy);
        w10[j] = (1.0f - fx) * fy;
        w11[j] = fx * fy;

        int lx = bx - cx0, ly = by - ry0;
        ok[j] = (lx >= 0) && (lx <= wcols - 2) && (ly >= 0) && (ly <= rows - 2);
        off[j]  = ly * SCOLS + lx;
        goff[j] = by * WW + bx;
    }

    const float* ibase = input + (size_t)b * CC * HWSZ;
    float* obase = out + (size_t)b * CC * HWSZ + (size_t)oy * WW + oxb;

    // ---- 2-phase double-buffered channel pipeline (T3-min + T14) ----
    f4 rbuf[KMAX];
    {   // prologue: issue channel-0 staging loads
        const float* src = ibase + ry0 * WW + cx0;
        #pragma unroll
        for (int k = 0; k < KMAX; ++k)
            if (sv[k]) rbuf[k] = *(const f4*)(src + sg[k]);
    }

    #pragma unroll
    for (int c = 0; c < CC; ++c) {
        float* Sb = &S[c & 1][0];
        // write staged regs -> LDS (vmcnt wait lands here, after prev compute)
        #pragma unroll
        for (int k = 0; k < KMAX; ++k) {
            if (sv[k]) {
                Sb[sl[k]]     = rbuf[k].x;     // ds_write2_b32 pairs
                Sb[sl[k] + 1] = rbuf[k].y;
                Sb[sl[k] + 2] = rbuf[k].z;
                Sb[sl[k] + 3] = rbuf[k].w;
            }
        }
        __syncthreads();   // single barrier per channel (double buffer)

        if (c + 1 < CC) {  // issue next channel's loads early; hide under compute
            const float* src = ibase + (c + 1) * HWSZ + ry0 * WW + cx0;
            #pragma unroll
            for (int k = 0; k < KMAX; ++k)
                if (sv[k]) rbuf[k] = *(const f4*)(src + sg[k]);
        }

        const float* p = ibase + c * HWSZ;
        f4 ov;
        #pragma unroll
        for (int j = 0; j < 4; ++j) {
            float v00, v01, v10, v11;
            if (ok[j]) {
                v00 = Sb[off[j]];               // ds_read2_b32 {0,1}
                v01 = Sb[off[j] + 1];
                v10 = Sb[off[j] + SCOLS];       // ds_read2_b32 {101,102}
                v11 = Sb[off[j] + SCOLS + 1];
            } else {
                f2 a, bb;   // exact global fallback (rare)
                __builtin_memcpy(&a,  p + goff[j], 8);
                __builtin_memcpy(&bb, p + goff[j] + WW, 8);
                v00 = a.x; v01 = a.y; v10 = bb.x; v11 = bb.y;
            }
            ov[j] = v00 * w00[j] + v01 * w01[j] + v10 * w10[j] + v11 * w11[j];
        }
        __builtin_nontemporal_store(ov, (f4*)(obase + c * HWSZ));
        // no second barrier: next iter writes the OTHER buffer; the write of
        // THIS buffer (iter c+2) is ordered behind iter c+1's barrier.
    }
}

extern "C" void kernel_launch(void* const* d_in, const int* in_sizes, int n_in,
                              void* d_out, int out_size, void* d_ws, size_t ws_size,
                              hipStream_t stream) {
    const float* input = (const float*)d_in[0];
    const float* theta = (const float*)d_in[1];
    float* out = (float*)d_out;

    dim3 block(256);
    dim3 grid(NBLK);   // 2048 blocks
    hipLaunchKernelGGL(st_lds4_kernel, grid, block, 0, stream,
                       input, theta, out);
}

// Round 8
// 54.769 us; speedup vs baseline: 1.2484x; 1.2484x over previous
//
#include <hip/hip_runtime.h>

#define BB 32
#define CC 16
#define HH 256
#define WW 256
#define HWSZ (HH * WW)

#define TW 16                  // tile width
#define TH 16                  // tile height
#define NBLK (BB * (WW/TW) * (HH/TH))   // 8192 blocks
#define NXCD 8

#define SROWS 26               // staged rows capacity
#define SCOLS 27               // ODD row stride -> stride-4 gather lanes spread 2-way (free)
#define PLANE (SROWS * SCOLS)  // 702 floats per channel
#define MAXF4 6                // staged cols <= 24

typedef float f2 __attribute__((ext_vector_type(2)));
typedef float f4 __attribute__((ext_vector_type(4)));

__global__ __launch_bounds__(256) void st_allch_kernel(
    const float* __restrict__ input,   // [B,C,H,W]
    const float* __restrict__ theta,   // [B,6]
    float* __restrict__ out)           // [B,C,H,W]
{
    __shared__ float S[CC * PLANE];    // 44.9 KB -> 3 blocks/CU

    // Chunked XCD swizzle (8192 % 8 == 0, bijective)
    int bid = blockIdx.x;
    int wg = (bid & (NXCD - 1)) * (NBLK / NXCD) + (bid >> 3);

    int b  = wg >> 8;              // 256 tiles per image
    int r  = wg & 255;
    int yt = r >> 4;               // 16 y-tiles
    int xt = r & 15;               // 16 x-tiles

    int tid = threadIdx.x;
    int g   = tid >> 6;            // channel group 0..3 -> channels 4g..4g+3
    int l   = tid & 63;
    int row = l >> 2;              // 0..15 row in tile
    int xq  = l & 3;               // 0..3 col-quad
    int oy  = yt * TH + row;
    int ox0 = xt * TW + xq * 4;    // 4 consecutive x-pixels (f4 store)

    const float* th = theta + b * 6;
    float t0 = th[0], t1 = th[1], t2 = th[2];
    float t3 = th[3], t4 = th[4], t5 = th[5];

    const float step = 2.0f / 255.0f;

    // ---- staging window from tile-corner bounds (affine + monotone clip) ----
    float gxa = -1.0f + (xt * TW) * step;
    float gxb = -1.0f + (xt * TW + TW - 1) * step;
    float gya = -1.0f + (yt * TH) * step;
    float gyb = -1.0f + (yt * TH + TH - 1) * step;

    float x00 = t0 * gxa + t1 * gya + t2, x01 = t0 * gxa + t1 * gyb + t2;
    float x10 = t0 * gxb + t1 * gya + t2, x11 = t0 * gxb + t1 * gyb + t2;
    float y00 = t3 * gxa + t4 * gya + t5, y01 = t3 * gxa + t4 * gyb + t5;
    float y10 = t3 * gxb + t4 * gya + t5, y11 = t3 * gxb + t4 * gyb + t5;

    float xmn = fminf(fminf(x00, x01), fminf(x10, x11));
    float xmx = fmaxf(fmaxf(x00, x01), fmaxf(x10, x11));
    float ymn = fminf(fminf(y00, y01), fminf(y10, y11));
    float ymx = fmaxf(fmaxf(y00, y01), fmaxf(y10, y11));
    xmn = fminf(fmaxf(xmn, -1.0f), 1.0f);
    xmx = fminf(fmaxf(xmx, -1.0f), 1.0f);
    ymn = fminf(fmaxf(ymn, -1.0f), 1.0f);
    ymx = fminf(fmaxf(ymx, -1.0f), 1.0f);
    float pxmn = (xmn + 1.0f) * 127.5f, pxmx = (xmx + 1.0f) * 127.5f;
    float pymn = (ymn + 1.0f) * 127.5f, pymx = (ymx + 1.0f) * 127.5f;

    int cx0 = (int)floorf(pxmn) - 1;
    cx0 = (max(0, min(cx0, WW - 4))) & ~3;              // 16B-aligned global start
    int cxend = min((int)floorf(pxmx) + 2, WW - 1);     // inclusive
    int wf4 = (cxend - cx0 + 4) >> 2;
    wf4 = min(wf4, min(MAXF4, (WW - cx0) >> 2));
    int wcols = wf4 * 4;

    int ry0 = (int)floorf(pymn) - 1;
    ry0 = max(0, min(ry0, HH - 1));
    int ryend = min((int)floorf(pymx) + 2, HH - 1);
    int rows = min(min(ryend - ry0 + 1, SROWS), HH - ry0);
    int nf4 = rows * wf4;                               // <= 26*6 = 156 < 256

    // ---- staging slot for this thread (one f4 per channel) ----
    bool valid = tid < nf4;
    int rr = tid / wf4;            // small runtime div, once
    int cq = tid - rr * wf4;
    int sgoff = rr * WW + cq * 4;      // global float offset within window
    int sloff = rr * SCOLS + cq * 4;   // LDS float offset (scalar writes)

    // ---- per-pixel offsets & weights (channel-invariant) ----
    int   off[4], goff[4];
    float w00[4], w01[4], w10[4], w11[4];
    bool  ok[4];
    float gy = -1.0f + oy * step;
    float cxp = t1 * gy + t2;
    float cyp = t4 * gy + t5;

    #pragma unroll
    for (int j = 0; j < 4; ++j) {
        float gx = -1.0f + (ox0 + j) * step;
        float xs = fminf(fmaxf(t0 * gx + cxp, -1.0f), 1.0f);
        float ys = fminf(fmaxf(t3 * gx + cyp, -1.0f), 1.0f);
        float x = (xs + 1.0f) * 127.5f;
        float y = (ys + 1.0f) * 127.5f;
        // bx=min(floor(x),254), fx=x-bx in [0,1]: exact index-clamp semantics
        float bxf = fminf(floorf(x), 254.0f);
        float byf = fminf(floorf(y), 254.0f);
        float fx = x - bxf, fy = y - byf;
        int bx = (int)bxf, by = (int)byf;

        w00[j] = (1.0f - fx) * (1.0f - fy);
        w01[j] = fx * (1.0f - fy);
        w10[j] = (1.0f - fx) * fy;
        w11[j] = fx * fy;

        int lx = bx - cx0, ly = by - ry0;
        ok[j] = (lx >= 0) && (lx <= wcols - 2) && (ly >= 0) && (ly <= rows - 2);
        off[j]  = ly * SCOLS + lx;
        goff[j] = by * WW + bx;
    }

    const float* ibase = input + (size_t)b * CC * HWSZ;
    float* obase = out + (size_t)b * CC * HWSZ + (size_t)oy * WW + ox0;

    // ---- stage ALL 16 channels, ONE barrier total ----
    f4 rb[CC];
    const float* wsrc = ibase + ry0 * WW + cx0;
    #pragma unroll
    for (int ch = 0; ch < CC; ++ch) {
        if (valid) rb[ch] = *(const f4*)(wsrc + ch * HWSZ + sgoff);
    }
    #pragma unroll
    for (int ch = 0; ch < CC; ++ch) {
        if (valid) {
            float* d = &S[ch * PLANE + sloff];
            d[0] = rb[ch].x;           // scalar b32 writes (SCOLS odd -> unaligned-safe)
            d[1] = rb[ch].y;
            d[2] = rb[ch].z;
            d[3] = rb[ch].w;
        }
    }
    __syncthreads();                   // the ONLY barrier

    // ---- gather + blend 4 channels x 4 px from LDS; no further sync ----
    #pragma unroll
    for (int u = 0; u < 4; ++u) {
        int c = g * 4 + u;
        const float* Sc = &S[c * PLANE];
        const float* p  = ibase + c * HWSZ;
        f4 ov;
        #pragma unroll
        for (int j = 0; j < 4; ++j) {
            float v00, v01, v10, v11;
            if (ok[j]) {
                v00 = Sc[off[j]];              // ds_read2_b32 {0,1}
                v01 = Sc[off[j] + 1];
                v10 = Sc[off[j] + SCOLS];      // ds_read2_b32 {27,28}
                v11 = Sc[off[j] + SCOLS + 1];
            } else {
                f2 a, bb;   // exact global fallback (per-block-rare -> execz skip)
                __builtin_memcpy(&a,  p + goff[j], 8);
                __builtin_memcpy(&bb, p + goff[j] + WW, 8);
                v00 = a.x; v01 = a.y; v10 = bb.x; v11 = bb.y;
            }
            ov[j] = v00 * w00[j] + v01 * w01[j] + v10 * w10[j] + v11 * w11[j];
        }
        __builtin_nontemporal_store(ov, (f4*)(obase + c * HWSZ));
    }
}

extern "C" void kernel_launch(void* const* d_in, const int* in_sizes, int n_in,
                              void* d_out, int out_size, void* d_ws, size_t ws_size,
                              hipStream_t stream) {
    const float* input = (const float*)d_in[0];
    const float* theta = (const float*)d_in[1];
    float* out = (float*)d_out;

    dim3 block(256);
    dim3 grid(NBLK);   // 8192 blocks
    hipLaunchKernelGGL(st_allch_kernel, grid, block, 0, stream,
                       input, theta, out);
}

// Round 9
// 49.428 us; speedup vs baseline: 1.3833x; 1.1081x over previous
//
#include <hip/hip_runtime.h>

#define BB 32
#define CC 16
#define HH 256
#define WW 256
#define HWSZ (HH * WW)

#define TW 16                  // tile width
#define TH 16                  // tile height
#define NBLK (BB * (WW/TW) * (HH/TH))   // 8192 blocks
#define NXCD 8

#define SROWS 23               // staged rows capacity (plane 621 -> 39.7 KB total, 4 blk/CU)
#define SCOLS 27               // ODD row stride -> stride-4 gather lanes spread 2-way (free)
#define PLANE (SROWS * SCOLS)  // 621 floats per channel
#define MAXF4 6                // staged cols <= 24

typedef float f2 __attribute__((ext_vector_type(2)));
typedef float f4 __attribute__((ext_vector_type(4)));

__global__ __launch_bounds__(256) void st_allch2_kernel(
    const float* __restrict__ input,   // [B,C,H,W]
    const float* __restrict__ theta,   // [B,6]
    float* __restrict__ out)           // [B,C,H,W]
{
    __shared__ float S[CC * PLANE];    // 39.7 KB -> 4 blocks/CU

    // Chunked XCD swizzle (8192 % 8 == 0, bijective). Consecutive wg (adjacent
    // x-tiles) stay on the SAME XCD -> their half-line output stores merge in
    // that XCD's L2 into full 128B lines (this is why stores are NOT nontemporal).
    int bid = blockIdx.x;
    int wg = (bid & (NXCD - 1)) * (NBLK / NXCD) + (bid >> 3);

    int b  = wg >> 8;              // 256 tiles per image
    int r  = wg & 255;
    int yt = r >> 4;               // 16 y-tiles
    int xt = r & 15;               // 16 x-tiles

    int tid = threadIdx.x;
    int g   = tid >> 6;            // channel group 0..3 -> channels 4g..4g+3
    int l   = tid & 63;
    int row = l >> 2;              // 0..15 row in tile
    int xq  = l & 3;               // 0..3 col-quad
    int oy  = yt * TH + row;
    int ox0 = xt * TW + xq * 4;    // 4 consecutive x-pixels (f4 store)

    const float* th = theta + b * 6;
    float t0 = th[0], t1 = th[1], t2 = th[2];
    float t3 = th[3], t4 = th[4], t5 = th[5];

    const float step = 2.0f / 255.0f;

    // ---- staging window from tile-corner bounds (affine + monotone clip) ----
    float gxa = -1.0f + (xt * TW) * step;
    float gxb = -1.0f + (xt * TW + TW - 1) * step;
    float gya = -1.0f + (yt * TH) * step;
    float gyb = -1.0f + (yt * TH + TH - 1) * step;

    float x00 = t0 * gxa + t1 * gya + t2, x01 = t0 * gxa + t1 * gyb + t2;
    float x10 = t0 * gxb + t1 * gya + t2, x11 = t0 * gxb + t1 * gyb + t2;
    float y00 = t3 * gxa + t4 * gya + t5, y01 = t3 * gxa + t4 * gyb + t5;
    float y10 = t3 * gxb + t4 * gya + t5, y11 = t3 * gxb + t4 * gyb + t5;

    float xmn = fminf(fminf(x00, x01), fminf(x10, x11));
    float xmx = fmaxf(fmaxf(x00, x01), fmaxf(x10, x11));
    float ymn = fminf(fminf(y00, y01), fminf(y10, y11));
    float ymx = fmaxf(fmaxf(y00, y01), fmaxf(y10, y11));
    xmn = fminf(fmaxf(xmn, -1.0f), 1.0f);
    xmx = fminf(fmaxf(xmx, -1.0f), 1.0f);
    ymn = fminf(fmaxf(ymn, -1.0f), 1.0f);
    ymx = fminf(fmaxf(ymx, -1.0f), 1.0f);
    float pxmn = (xmn + 1.0f) * 127.5f, pxmx = (xmx + 1.0f) * 127.5f;
    float pymn = (ymn + 1.0f) * 127.5f, pymx = (ymx + 1.0f) * 127.5f;

    int cx0 = (int)floorf(pxmn) - 1;
    cx0 = (max(0, min(cx0, WW - 4))) & ~3;              // 16B-aligned global start
    int cxend = min((int)floorf(pxmx) + 2, WW - 1);     // inclusive
    int wf4 = (cxend - cx0 + 4) >> 2;
    wf4 = min(wf4, min(MAXF4, (WW - cx0) >> 2));
    int wcols = wf4 * 4;

    int ry0 = (int)floorf(pymn) - 1;
    ry0 = max(0, min(ry0, HH - 1));
    int ryend = min((int)floorf(pymx) + 2, HH - 1);
    int rows = min(min(ryend - ry0 + 1, SROWS), HH - ry0);
    int nf4 = rows * wf4;                               // <= 23*6 = 138 < 256

    // ---- staging slot for this thread (one f4 per channel) ----
    bool valid = tid < nf4;
    int rr = tid / wf4;            // small runtime div, once
    int cq = tid - rr * wf4;
    int sgoff = rr * WW + cq * 4;      // global float offset within window
    int sloff = rr * SCOLS + cq * 4;   // LDS float offset (scalar writes)

    // ---- per-pixel offsets & weights (channel-invariant) ----
    int   off[4], goff[4];
    float w00[4], w01[4], w10[4], w11[4];
    bool  ok[4];
    float gy = -1.0f + oy * step;
    float cxp = t1 * gy + t2;
    float cyp = t4 * gy + t5;

    #pragma unroll
    for (int j = 0; j < 4; ++j) {
        float gx = -1.0f + (ox0 + j) * step;
        float xs = fminf(fmaxf(t0 * gx + cxp, -1.0f), 1.0f);
        float ys = fminf(fmaxf(t3 * gx + cyp, -1.0f), 1.0f);
        float x = (xs + 1.0f) * 127.5f;
        float y = (ys + 1.0f) * 127.5f;
        // bx=min(floor(x),254), fx=x-bx in [0,1]: exact index-clamp semantics
        float bxf = fminf(floorf(x), 254.0f);
        float byf = fminf(floorf(y), 254.0f);
        float fx = x - bxf, fy = y - byf;
        int bx = (int)bxf, by = (int)byf;

        w00[j] = (1.0f - fx) * (1.0f - fy);
        w01[j] = fx * (1.0f - fy);
        w10[j] = (1.0f - fx) * fy;
        w11[j] = fx * fy;

        int lx = bx - cx0, ly = by - ry0;
        ok[j] = (lx >= 0) && (lx <= wcols - 2) && (ly >= 0) && (ly <= rows - 2);
        off[j]  = ly * SCOLS + lx;
        goff[j] = by * WW + bx;
    }

    const float* ibase = input + (size_t)b * CC * HWSZ;
    float* obase = out + (size_t)b * CC * HWSZ + (size_t)oy * WW + ox0;

    // ---- stage ALL 16 channels, ONE barrier total ----
    f4 rb[CC];
    const float* wsrc = ibase + ry0 * WW + cx0;
    #pragma unroll
    for (int ch = 0; ch < CC; ++ch) {
        if (valid) rb[ch] = *(const f4*)(wsrc + ch * HWSZ + sgoff);
    }
    #pragma unroll
    for (int ch = 0; ch < CC; ++ch) {
        if (valid) {
            float* d = &S[ch * PLANE + sloff];
            d[0] = rb[ch].x;           // scalar b32 writes (one-time)
            d[1] = rb[ch].y;
            d[2] = rb[ch].z;
            d[3] = rb[ch].w;
        }
    }
    __syncthreads();                   // the ONLY barrier

    // ---- gather + blend 4 channels x 4 px from LDS; no further sync ----
    #pragma unroll
    for (int u = 0; u < 4; ++u) {
        int c = g * 4 + u;
        const float* Sc = &S[c * PLANE];
        const float* p  = ibase + c * HWSZ;
        f4 ov;
        #pragma unroll
        for (int j = 0; j < 4; ++j) {
            float v00, v01, v10, v11;
            if (ok[j]) {
                v00 = Sc[off[j]];              // ds_read2_b32 {0,1}
                v01 = Sc[off[j] + 1];
                v10 = Sc[off[j] + SCOLS];      // ds_read2_b32 {27,28}
                v11 = Sc[off[j] + SCOLS + 1];
            } else {
                f2 a, bb;   // exact global fallback (rare, per-pixel)
                __builtin_memcpy(&a,  p + goff[j], 8);
                __builtin_memcpy(&bb, p + goff[j] + WW, 8);
                v00 = a.x; v01 = a.y; v10 = bb.x; v11 = bb.y;
            }
            ov[j] = v00 * w00[j] + v01 * w01[j] + v10 * w10[j] + v11 * w11[j];
        }
        // PLAIN store (not NT): half-lines from adjacent tiles merge in L2.
        *(f4*)(obase + c * HWSZ) = ov;
    }
}

extern "C" void kernel_launch(void* const* d_in, const int* in_sizes, int n_in,
                              void* d_out, int out_size, void* d_ws, size_t ws_size,
                              hipStream_t stream) {
    const float* input = (const float*)d_in[0];
    const float* theta = (const float*)d_in[1];
    float* out = (float*)d_out;

    dim3 block(256);
    dim3 grid(NBLK);   // 8192 blocks
    hipLaunchKernelGGL(st_allch2_kernel, grid, block, 0, stream,
                       input, theta, out);
}

// Round 10
// 46.116 us; speedup vs baseline: 1.4827x; 1.0718x over previous
//
#include <hip/hip_runtime.h>

#define BB 32
#define CC 16
#define HH 256
#define WW 256
#define HWSZ (HH * WW)

#define TW 16                  // tile width
#define TH 16                  // tile height
#define CHB 8                  // channels per block (16 ch split across 2 blocks)
#define NBLK (BB * (WW/TW) * (HH/TH) * 2)   // 16384 blocks
#define NXCD 8

#define SROWS 23               // staged rows capacity
#define SCOLS 27               // ODD row stride -> stride-4 gather lanes spread ~2-way
#define PLANE (SROWS * SCOLS)  // 621 floats per channel
#define MAXF4 6                // staged cols <= 24

typedef float f2 __attribute__((ext_vector_type(2)));
typedef float f4 __attribute__((ext_vector_type(4)));

__global__ __launch_bounds__(256, 8) void st_half_kernel(
    const float* __restrict__ input,   // [B,C,H,W]
    const float* __restrict__ theta,   // [B,6]
    float* __restrict__ out)           // [B,C,H,W]
{
    __shared__ float S[CHB * PLANE];   // 19.9 KB -> 8 blocks/CU (100% occ cap)

    // Chunked XCD swizzle (16384 % 8 == 0, bijective). Adjacent tiles (and the
    // two channel-halves of one tile) stay on the same XCD -> half-line output
    // stores merge in its L2 (plain stores, NOT nontemporal — R9 win).
    int bid = blockIdx.x;
    int wg = (bid & (NXCD - 1)) * (NBLK / NXCD) + (bid >> 3);

    int b  = wg >> 9;              // 512 (tile,half) units per image
    int r  = wg & 511;
    int yt = r >> 5;               // 16 y-tiles
    int xt = (r >> 1) & 15;        // 16 x-tiles
    int h  = r & 1;                // channel half: channels h*8 .. h*8+7

    int tid = threadIdx.x;
    int g   = tid >> 6;            // wave id 0..3 -> channels h*8 + 2g, +1
    int l   = tid & 63;
    int row = l >> 2;              // 0..15 row in tile
    int xq  = l & 3;               // 0..3 col-quad
    int oy  = yt * TH + row;
    int ox0 = xt * TW + xq * 4;    // 4 consecutive x-pixels (f4 store)

    const float* th = theta + b * 6;
    float t0 = th[0], t1 = th[1], t2 = th[2];
    float t3 = th[3], t4 = th[4], t5 = th[5];

    const float step = 2.0f / 255.0f;

    // ---- staging window from tile-corner bounds (affine + monotone clip) ----
    float gxa = -1.0f + (xt * TW) * step;
    float gxb = -1.0f + (xt * TW + TW - 1) * step;
    float gya = -1.0f + (yt * TH) * step;
    float gyb = -1.0f + (yt * TH + TH - 1) * step;

    float x00 = t0 * gxa + t1 * gya + t2, x01 = t0 * gxa + t1 * gyb + t2;
    float x10 = t0 * gxb + t1 * gya + t2, x11 = t0 * gxb + t1 * gyb + t2;
    float y00 = t3 * gxa + t4 * gya + t5, y01 = t3 * gxa + t4 * gyb + t5;
    float y10 = t3 * gxb + t4 * gya + t5, y11 = t3 * gxb + t4 * gyb + t5;

    float xmn = fminf(fminf(x00, x01), fminf(x10, x11));
    float xmx = fmaxf(fmaxf(x00, x01), fmaxf(x10, x11));
    float ymn = fminf(fminf(y00, y01), fminf(y10, y11));
    float ymx = fmaxf(fmaxf(y00, y01), fmaxf(y10, y11));
    xmn = fminf(fmaxf(xmn, -1.0f), 1.0f);
    xmx = fminf(fmaxf(xmx, -1.0f), 1.0f);
    ymn = fminf(fmaxf(ymn, -1.0f), 1.0f);
    ymx = fminf(fmaxf(ymx, -1.0f), 1.0f);
    float pxmn = (xmn + 1.0f) * 127.5f, pxmx = (xmx + 1.0f) * 127.5f;
    float pymn = (ymn + 1.0f) * 127.5f, pymx = (ymx + 1.0f) * 127.5f;

    int cx0 = (int)floorf(pxmn) - 1;
    cx0 = (max(0, min(cx0, WW - 4))) & ~3;              // 16B-aligned global start
    int cxend = min((int)floorf(pxmx) + 2, WW - 1);     // inclusive
    int wf4 = (cxend - cx0 + 4) >> 2;
    wf4 = min(wf4, min(MAXF4, (WW - cx0) >> 2));
    int wcols = wf4 * 4;

    int ry0 = (int)floorf(pymn) - 1;
    ry0 = max(0, min(ry0, HH - 1));
    int ryend = min((int)floorf(pymx) + 2, HH - 1);
    int rows = min(min(ryend - ry0 + 1, SROWS), HH - ry0);
    int nf4 = rows * wf4;                               // <= 23*6 = 138 < 256

    // ---- staging slot for this thread (one f4 per channel) ----
    bool valid = tid < nf4;
    int rr = tid / wf4;            // small runtime div, once
    int cq = tid - rr * wf4;
    int sgoff = rr * WW + cq * 4;      // global float offset within window
    int sloff = rr * SCOLS + cq * 4;   // LDS float offset (scalar writes)

    // ---- per-pixel offsets & weights (channel-invariant) ----
    int   off[4], goff[4];
    float w00[4], w01[4], w10[4], w11[4];
    bool  ok[4];
    float gy = -1.0f + oy * step;
    float cxp = t1 * gy + t2;
    float cyp = t4 * gy + t5;

    #pragma unroll
    for (int j = 0; j < 4; ++j) {
        float gx = -1.0f + (ox0 + j) * step;
        float xs = fminf(fmaxf(t0 * gx + cxp, -1.0f), 1.0f);
        float ys = fminf(fmaxf(t3 * gx + cyp, -1.0f), 1.0f);
        float x = (xs + 1.0f) * 127.5f;
        float y = (ys + 1.0f) * 127.5f;
        // bx=min(floor(x),254), fx=x-bx in [0,1]: exact index-clamp semantics
        float bxf = fminf(floorf(x), 254.0f);
        float byf = fminf(floorf(y), 254.0f);
        float fx = x - bxf, fy = y - byf;
        int bx = (int)bxf, by = (int)byf;

        w00[j] = (1.0f - fx) * (1.0f - fy);
        w01[j] = fx * (1.0f - fy);
        w10[j] = (1.0f - fx) * fy;
        w11[j] = fx * fy;

        int lx = bx - cx0, ly = by - ry0;
        ok[j] = (lx >= 0) && (lx <= wcols - 2) && (ly >= 0) && (ly <= rows - 2);
        off[j]  = ly * SCOLS + lx;
        goff[j] = by * WW + bx;
    }

    const float* ibase = input + (size_t)b * CC * HWSZ + (size_t)h * CHB * HWSZ;
    float* obase = out + (size_t)b * CC * HWSZ + (size_t)h * CHB * HWSZ
                       + (size_t)oy * WW + ox0;

    // ---- stage this half's 8 channels, ONE barrier total ----
    f4 rb[CHB];
    const float* wsrc = ibase + ry0 * WW + cx0;
    #pragma unroll
    for (int ch = 0; ch < CHB; ++ch) {
        if (valid) rb[ch] = *(const f4*)(wsrc + ch * HWSZ + sgoff);
    }
    #pragma unroll
    for (int ch = 0; ch < CHB; ++ch) {
        if (valid) {
            float* d = &S[ch * PLANE + sloff];
            d[0] = rb[ch].x;           // ds_write2_b32 pairs (one-time)
            d[1] = rb[ch].y;
            d[2] = rb[ch].z;
            d[3] = rb[ch].w;
        }
    }
    __syncthreads();                   // the ONLY barrier

    // ---- gather + blend 2 channels x 4 px from LDS; no further sync ----
    #pragma unroll
    for (int u = 0; u < 2; ++u) {
        int c = g * 2 + u;             // local channel 0..7
        const float* Sc = &S[c * PLANE];
        const float* p  = ibase + c * HWSZ;
        f4 ov;
        #pragma unroll
        for (int j = 0; j < 4; ++j) {
            float v00, v01, v10, v11;
            if (ok[j]) {
                v00 = Sc[off[j]];              // ds_read2_b32 {0,1}
                v01 = Sc[off[j] + 1];
                v10 = Sc[off[j] + SCOLS];      // ds_read2_b32 {27,28}
                v11 = Sc[off[j] + SCOLS + 1];
            } else {
                f2 a, bb;   // exact global fallback (rare, per-pixel)
                __builtin_memcpy(&a,  p + goff[j], 8);
                __builtin_memcpy(&bb, p + goff[j] + WW, 8);
                v00 = a.x; v01 = a.y; v10 = bb.x; v11 = bb.y;
            }
            ov[j] = v00 * w00[j] + v01 * w01[j] + v10 * w10[j] + v11 * w11[j];
        }
        // PLAIN store: half-lines from adjacent tiles merge in L2.
        *(f4*)(obase + c * HWSZ) = ov;
    }
}

extern "C" void kernel_launch(void* const* d_in, const int* in_sizes, int n_in,
                              void* d_out, int out_size, void* d_ws, size_t ws_size,
                              hipStream_t stream) {
    const float* input = (const float*)d_in[0];
    const float* theta = (const float*)d_in[1];
    float* out = (float*)d_out;

    dim3 block(256);
    dim3 grid(NBLK);   // 16384 blocks
    hipLaunchKernelGGL(st_half_kernel, grid, block, 0, stream,
                       input, theta, out);
}